// Round 9
// baseline (88.650 us; speedup 1.0000x reference)
//
#include <hip/hip_runtime.h>
#include <hip/hip_fp16.h>
#include <math.h>

#define TB 2048
#define TK 128
#define TD 512
#define DSPLIT 32
#define DLEN 16            // TD / DSPLIT
#define BROWS 64
#define NRB (TB / BROWS)   // 32
#define SLICE ((size_t)DSPLIT * TB * TK)   // elems per part slice (16 MB as f16)

// DIAGNOSTIC ROUND: kernels identical to R8 in math; grid is replicated REP x
// with per-replica ws slices so each kernel's true duration = measured / REP
// and both rise above the harness's 42 us poison fills in the top-5 view.

// ---------------------------------------------------------------------------
__global__ __launch_bounds__(128, 2) void dist_kernel(
        const float* __restrict__ x, const float* __restrict__ C,
        const float* __restrict__ Dm, __half* __restrict__ part,
        float* __restrict__ logdet_part, int nrep_inner) {
    __shared__ float sa[DLEN][TK];    // 8 KB : u = rsqrt(|D|+eps), [d][k]
    __shared__ float sb[DLEN][TK];    // 8 KB : c*u, [d][k]
    __shared__ float xs[DLEN][BROWS]; // 4 KB : x transposed, [d][row]

    const int tid = threadIdx.x;
    const int rep = blockIdx.x / nrep_inner;     // replica id
    const int inner = blockIdx.x % nrep_inner;
    const int rb = inner / DSPLIT;
    const int ds = inner % DSPLIT;
    const int b0 = rb * BROWS;
    const int d0 = ds * DLEN;
    __half* prt = part + (size_t)rep * SLICE;

    // ---- stage x transposed: 64 rows x 16 d = 256 f4, 2 per thread ----
    #pragma unroll
    for (int i = 0; i < 2; ++i) {
        int f = i * 128 + tid;
        int row = f >> 2;
        int dq = (f & 3) * 4;
        float4 v = *reinterpret_cast<const float4*>(
            &x[(size_t)(b0 + row) * TD + d0 + dq]);
        xs[dq + 0][row] = v.x;
        xs[dq + 1][row] = v.y;
        xs[dq + 2][row] = v.z;
        xs[dq + 3][row] = v.w;
    }

    // ---- stage params: 128 k x 4 f4 per array, 4 per thread (coalesced) ----
    #pragma unroll
    for (int i = 0; i < 4; ++i) {
        int f = i * 128 + tid;
        int k = f >> 2;
        int j = f & 3;
        float4 dv = *reinterpret_cast<const float4*>(&Dm[(size_t)k * TD + d0 + j * 4]);
        float4 cv = *reinterpret_cast<const float4*>(&C[(size_t)k * TD + d0 + j * 4]);
        float da0 = fabsf(dv.x) + 1e-8f, u0 = rsqrtf(da0);
        float da1 = fabsf(dv.y) + 1e-8f, u1 = rsqrtf(da1);
        float da2 = fabsf(dv.z) + 1e-8f, u2 = rsqrtf(da2);
        float da3 = fabsf(dv.w) + 1e-8f, u3 = rsqrtf(da3);
        int db = j * 4;
        sa[db + 0][k] = u0; sb[db + 0][k] = cv.x * u0;
        sa[db + 1][k] = u1; sb[db + 1][k] = cv.y * u1;
        sa[db + 2][k] = u2; sb[db + 2][k] = cv.z * u2;
        sa[db + 3][k] = u3; sb[db + 3][k] = cv.w * u3;
        if (rb == 0) {
            float ls = logf(da0) + logf(da1) + logf(da2) + logf(da3);
            ls += __shfl_xor(ls, 1, 64);
            ls += __shfl_xor(ls, 2, 64);
            // replicas race with identical values: benign
            if ((tid & 3) == 0) logdet_part[ds * TK + k] = -0.5f * ls;
        }
    }
    __syncthreads();

    const int k0 = (tid & 31) * 4;
    const int r0 = (tid >> 5) * 16;

    float acc[16][4];
    #pragma unroll
    for (int r = 0; r < 16; ++r)
        #pragma unroll
        for (int k = 0; k < 4; ++k) acc[r][k] = 0.f;

#define ROWFMA(XR, R)                                                      \
    { float t;                                                             \
      t = fmaf(XR, u4.x, -c4.x); acc[R][0] = fmaf(t, t, acc[R][0]);        \
      t = fmaf(XR, u4.y, -c4.y); acc[R][1] = fmaf(t, t, acc[R][1]);        \
      t = fmaf(XR, u4.z, -c4.z); acc[R][2] = fmaf(t, t, acc[R][2]);        \
      t = fmaf(XR, u4.w, -c4.w); acc[R][3] = fmaf(t, t, acc[R][3]); }

    #pragma unroll
    for (int d = 0; d < DLEN; ++d) {
        const float4 u4 = *reinterpret_cast<const float4*>(&sa[d][k0]);
        const float4 c4 = *reinterpret_cast<const float4*>(&sb[d][k0]);
        const float4 xv0 = *reinterpret_cast<const float4*>(&xs[d][r0]);
        const float4 xv1 = *reinterpret_cast<const float4*>(&xs[d][r0 + 4]);
        const float4 xv2 = *reinterpret_cast<const float4*>(&xs[d][r0 + 8]);
        const float4 xv3 = *reinterpret_cast<const float4*>(&xs[d][r0 + 12]);
        ROWFMA(xv0.x, 0)  ROWFMA(xv0.y, 1)  ROWFMA(xv0.z, 2)  ROWFMA(xv0.w, 3)
        ROWFMA(xv1.x, 4)  ROWFMA(xv1.y, 5)  ROWFMA(xv1.z, 6)  ROWFMA(xv1.w, 7)
        ROWFMA(xv2.x, 8)  ROWFMA(xv2.y, 9)  ROWFMA(xv2.z, 10) ROWFMA(xv2.w, 11)
        ROWFMA(xv3.x, 12) ROWFMA(xv3.y, 13) ROWFMA(xv3.z, 14) ROWFMA(xv3.w, 15)
    }
#undef ROWFMA

    #pragma unroll
    for (int r = 0; r < 16; ++r) {
        __half2 h0 = __floats2half2_rn(acc[r][0], acc[r][1]);
        __half2 h1 = __floats2half2_rn(acc[r][2], acc[r][3]);
        uint2 pk;
        pk.x = *reinterpret_cast<unsigned int*>(&h0);
        pk.y = *reinterpret_cast<unsigned int*>(&h1);
        *reinterpret_cast<uint2*>(
            &prt[((size_t)ds * TB + b0 + r0 + r) * TK + k0]) = pk;
    }
}

// ---------------------------------------------------------------------------
__global__ __launch_bounds__(256) void finish_kernel(
        const __half* __restrict__ part, const float* __restrict__ logdet_part,
        float* __restrict__ out, int nblk_inner) {
    const int rep = blockIdx.x / nblk_inner;
    const int bblk = blockIdx.x % nblk_inner;
    const int lane = threadIdx.x & 63;
    const int wv = threadIdx.x >> 6;
    const int b = bblk * 4 + wv;
    const int k0 = lane * 2;

    const __half2* ph = reinterpret_cast<const __half2*>(part + (size_t)rep * SLICE);

    float d0 = 0.f, d1 = 0.f;
    float det0 = 0.f, det1 = 0.f;
    #pragma unroll 8
    for (int s = 0; s < DSPLIT; ++s) {
        float2 p = __half22float2(ph[(((size_t)s * TB + b) * TK >> 1) + lane]);
        d0 += p.x; d1 += p.y;
        float2 dt = *reinterpret_cast<const float2*>(&logdet_part[s * TK + k0]);
        det0 += dt.x; det1 += dt.y;
    }
    float s0 = fmaf(-0.5f, d0, det0);
    float s1 = fmaf(-0.5f, d1, det1);

    float m = fmaxf(s0, s1);
    #pragma unroll
    for (int msk = 32; msk >= 1; msk >>= 1) m = fmaxf(m, __shfl_xor(m, msk, 64));
    float p0 = expf(s0 - m), p1 = expf(s1 - m);
    float ps = p0 + p1;
    #pragma unroll
    for (int msk = 32; msk >= 1; msk >>= 1) ps += __shfl_xor(ps, msk, 64);
    float lse = logf(ps) + m;

    const float LOGC = -18.420680743952367f;  // ln(1e-8)
    float2 o;
    o.x = fmaxf(s0 - lse, LOGC);
    o.y = fmaxf(s1 - lse, LOGC);
    *reinterpret_cast<float2*>(&out[(size_t)b * TK + k0]) = o;  // replicas: identical values

    float bv; int bi; float bd;
    if (s1 > s0) { bv = s1; bi = k0 + 1; bd = d1; }
    else         { bv = s0; bi = k0;     bd = d0; }
    #pragma unroll
    for (int msk = 32; msk >= 1; msk >>= 1) {
        float ov = __shfl_xor(bv, msk, 64);
        int   oi = __shfl_xor(bi, msk, 64);
        float od = __shfl_xor(bd, msk, 64);
        if (ov > bv || (ov == bv && oi < bi)) { bv = ov; bi = oi; bd = od; }
    }
    if (lane == 0) out[(size_t)TB * TK + b] = sqrtf(bd);
}

// ---------------------------------------------------------------------------
extern "C" void kernel_launch(void* const* d_in, const int* in_sizes, int n_in,
                              void* d_out, int out_size, void* d_ws, size_t ws_size,
                              hipStream_t stream) {
    const float* x  = (const float*)d_in[0];
    const float* C  = (const float*)d_in[1];
    const float* Dm = (const float*)d_in[2];
    float* out = (float*)d_out;

    // Diagnostic replication factor (per-replica ws slices).
    const size_t need8 = 8 * SLICE * sizeof(__half) + (64 << 10);
    const int REP = (ws_size >= need8) ? 8 : 1;

    __half* part       = (__half*)d_ws;
    float* logdet_part = (float*)((char*)d_ws + (size_t)REP * SLICE * sizeof(__half));

    dist_kernel<<<NRB * DSPLIT * REP, 128, 0, stream>>>(
        x, C, Dm, part, logdet_part, NRB * DSPLIT);
    finish_kernel<<<(TB / 4) * REP, 256, 0, stream>>>(
        part, logdet_part, out, TB / 4);
}